// Round 19
// baseline (534.582 us; speedup 1.0000x reference)
//
#include <hip/hip_runtime.h>

// Problem constants (fixed by reference)
#define BB 256      // batch
#define TT 1024     // time steps
#define HH 32       // hidden
#define SS 8        // superstep length (steps per barrier)
#define NBK (TT/SS) // 128 blocks of 8 steps
#define NSS (NBK+9) // 137 supersteps (10-stage skew)
#define NT 1024     // 16 waves, 4/SIMD
#define SP 32       // stream row stride (floats)
#define GP 96       // gi row stride
#define EPB 2       // batch elements per block

// R19 = R18 structure + TWO batch elements per block (grid 256->128).
// Diagnosis (R15/R17/R18): wall = gh serial chain LATENCY (VALUBusy fell
// 81.5->68.6% at constant wall when issue was cut). Fix: interleave two
// independent recurrences (b0,b1) in each gh wave — weights SHARED (no new
// weight arrays; R12/R14/R16 spills all came from weight-register growth),
// only +v_h1 and +4 accumulators. ff waves loop both elements (2-4x slack).
// SS 16->8 keeps LDS at 61.4KB (barrier frequency proven free, R6/R10).
//
// Superstep n schedule (one barrier per superstep; each stage does BOTH
// elements of its block):
//   wv12 : emb gather blk n     -> ebuf[e]
//   wv9  : y1  blk n-1          -> y1s[e]   (2 steps/iter)
//   wv10 : y2  blk n-2          -> y2s[e]   (2 steps/iter)
//   wv11 : y3  blk n-3          -> y3s[e]   (2 steps/iter)
//   wv3/6: gi0 A/B blk n-4      -> gib[0][e]
//   wv0  : gh0+gates blk n-5    -> h0s[e]   (8 serial step-pairs, PRIO)
//   wv4/7: gi1 A/B blk n-6      -> gib[1][e]
//   wv1  : gh1+gates blk n-7    -> h1s[e]                         (PRIO)
//   wv5/8: gi2 A/B blk n-8      -> gib[2][e]
//   wv2  : gh2+gates blk n-9    -> out_seq[e]                     (PRIO)
//   wv13-15: idle (barrier only)

__device__ __forceinline__ float fast_rcp(float x) { return __builtin_amdgcn_rcpf(x); }
__device__ __forceinline__ float sigm(float x)     { return fast_rcp(1.f + __expf(-x)); }
__device__ __forceinline__ float tanh_fast(float x){ float e = __expf(2.f * x); return 1.f - 2.f * fast_rcp(e + 1.f); }
__device__ __forceinline__ float rlane(float v, int k) {
    return __int_as_float(__builtin_amdgcn_readlane(__float_as_int(v), k));
}

__global__ __launch_bounds__(NT, 4) void rnn_fused(
    const int*   __restrict__ xidx,   // [B,T]
    const float* __restrict__ hid,    // [L,B,H]
    const float* __restrict__ emb,    // [38000,H]
    const float* __restrict__ W1, const float* __restrict__ b1,
    const float* __restrict__ W2, const float* __restrict__ b2,
    const float* __restrict__ W3, const float* __restrict__ b3,
    const float* __restrict__ Wih,    // [L,3H,H]
    const float* __restrict__ Whh,    // [L,3H,H]
    const float* __restrict__ bih,    // [L,3H]
    const float* __restrict__ bhh,    // [L,3H]
    float*       __restrict__ out)    // [B*T*H] ++ [L*B*H]
{
    const int b0  = blockIdx.x * EPB;        // first batch element
    const int tid = threadIdx.x;
    const int wv  = tid >> 6;
    const int ln  = tid & 63;
    const int lo  = ln & 31;
    const int hh  = ln >> 5;                 // lane half (paired ff waves)

    __shared__ alignas(16) float ebuf[EPB][2][SS][SP];
    __shared__ alignas(16) float y1s [EPB][2][SS][SP];
    __shared__ alignas(16) float y2s [EPB][2][SS][SP];
    __shared__ alignas(16) float y3s [EPB][2][SS][SP];
    __shared__ alignas(16) float h0s [EPB][2][SS][SP];
    __shared__ alignas(16) float h1s [EPB][2][SS][SP];
    __shared__ alignas(16) float gib [3][EPB][2][SS][GP];

    // ---------------- per-role register-resident weights ----------------
    float wA[32], wB[32];
    float biasA = 0.f, biasB = 0.f;
    float v_h0 = 0.f, v_h1 = 0.f;            // two recurrence states (gh only)

    if (wv < 3) {                       // gh: Whh rows {ln} and {64+lo} (shared)
        const float4* pA = reinterpret_cast<const float4*>(Whh + (size_t)(wv * 96 + ln) * HH);
        const float4* pB = reinterpret_cast<const float4*>(Whh + (size_t)(wv * 96 + 64 + lo) * HH);
        #pragma unroll
        for (int i = 0; i < 8; ++i) {
            reinterpret_cast<float4*>(wA)[i] = pA[i];
            reinterpret_cast<float4*>(wB)[i] = pB[i];
        }
        biasA = bhh[wv * 96 + ln];
        biasB = bhh[wv * 96 + 64 + lo];
        if (ln < HH) {
            v_h0 = hid[(size_t)(wv * BB + b0    ) * HH + ln];
            v_h1 = hid[(size_t)(wv * BB + b0 + 1) * HH + ln];
        }
    } else if (wv < 6) {                // giA: Wih row ln (rows 0-63)
        const int l = wv - 3;
        const float4* pA = reinterpret_cast<const float4*>(Wih + (size_t)(l * 96 + ln) * HH);
        #pragma unroll
        for (int i = 0; i < 8; ++i) reinterpret_cast<float4*>(wA)[i] = pA[i];
        biasA = bih[l * 96 + ln];
    } else if (wv < 9) {                // giB: Wih row 64+lo (n rows)
        const int l = wv - 6;
        const float4* pA = reinterpret_cast<const float4*>(Wih + (size_t)(l * 96 + 64 + lo) * HH);
        #pragma unroll
        for (int i = 0; i < 8; ++i) reinterpret_cast<float4*>(wA)[i] = pA[i];
        biasA = bih[l * 96 + 64 + lo];
    } else if (wv < 12) {               // y1/y2/y3: W row lo
        const float* Ws = (wv == 9) ? W1 : (wv == 10) ? W2 : W3;
        const float* bs = (wv == 9) ? b1 : (wv == 10) ? b2 : b3;
        const float4* pA = reinterpret_cast<const float4*>(Ws + (size_t)lo * HH);
        #pragma unroll
        for (int i = 0; i < 8; ++i) reinterpret_cast<float4*>(wA)[i] = pA[i];
        biasA = bs[lo];
    }
    __syncthreads();

    float* const out_hf = out + (size_t)BB * TT * HH;

    for (int n = 0; n < NSS; ++n) {
        if (wv < 3) {
            // ====== gh wave, layer wv: 8 serial step-pairs (b0 + b1) ===========
            const int blk = n - 5 - 2 * wv;
            if (blk >= 0 && blk < NBK) {
                const int p = blk & 1;
                const float* g0 = &gib[wv][0][p][0][0];
                const float* g1 = &gib[wv][1][p][0][0];
                __builtin_amdgcn_s_setprio(1);
                for (int t2 = 0; t2 < SS; ++t2) {
                    const float giA0 = g0[t2 * GP + ln];
                    const float giB0 = g0[t2 * GP + 64 + lo];
                    const float giA1 = g1[t2 * GP + ln];
                    const float giB1 = g1[t2 * GP + 64 + lo];
                    float a0 = biasA, a1 = 0.f, c0 = biasB, c1 = 0.f;   // b0
                    float d0 = biasA, d1 = 0.f, e0 = biasB, e1 = 0.f;   // b1
                    #pragma unroll
                    for (int k = 0; k < 32; k += 2) {
                        const float h00 = rlane(v_h0, k), h01 = rlane(v_h0, k + 1);
                        const float h10 = rlane(v_h1, k), h11 = rlane(v_h1, k + 1);
                        a0 = fmaf(wA[k],     h00, a0);
                        a1 = fmaf(wA[k + 1], h01, a1);
                        c0 = fmaf(wB[k],     h00, c0);
                        c1 = fmaf(wB[k + 1], h01, c1);
                        d0 = fmaf(wA[k],     h10, d0);
                        d1 = fmaf(wA[k + 1], h11, d1);
                        e0 = fmaf(wB[k],     h10, e0);
                        e1 = fmaf(wB[k + 1], h11, e1);
                    }
                    // gates, element 0 and 1 (chains interleave on the SIMD)
                    const float sA0  = giA0 + a0 + a1;
                    const float sA1  = giA1 + d0 + d1;
                    const float ghB0 = c0 + c1;
                    const float ghB1 = e0 + e1;
                    const float zp0  = __shfl_xor(sA0, 32);
                    const float zp1  = __shfl_xor(sA1, 32);
                    const float r0   = sigm(sA0);
                    const float r1   = sigm(sA1);
                    const float z0   = sigm(zp0);
                    const float z1   = sigm(zp1);
                    const float nn0  = tanh_fast(fmaf(r0, ghB0, giB0));
                    const float nn1  = tanh_fast(fmaf(r1, ghB1, giB1));
                    const float hn0  = fmaf(z0, v_h0 - nn0, nn0);
                    const float hn1  = fmaf(z1, v_h1 - nn1, nn1);
                    v_h0 = hn0;
                    v_h1 = hn1;
                    if (ln < HH) {
                        if (wv == 0) {
                            h0s[0][p][t2][ln] = hn0;
                            h0s[1][p][t2][ln] = hn1;
                        } else if (wv == 1) {
                            h1s[0][p][t2][ln] = hn0;
                            h1s[1][p][t2][ln] = hn1;
                        } else {
                            const size_t off = (size_t)(blk * SS + t2) * HH + ln;
                            out[(size_t)(b0    ) * TT * HH + off] = hn0;
                            out[(size_t)(b0 + 1) * TT * HH + off] = hn1;
                        }
                    }
                }
                __builtin_amdgcn_s_setprio(0);
            }
        } else if (wv < 6) {
            // ====== giA wave, layer l: rows 0-63, both elements ================
            const int l   = wv - 3;
            const int blk = n - 4 - 2 * l;
            if (blk >= 0 && blk < NBK) {
                const int p = blk & 1;
                for (int e = 0; e < EPB; ++e) {
                    const float* xs = (l == 0) ? &y3s[e][p][0][0]
                                    : (l == 1) ? &h0s[e][p][0][0]
                                               : &h1s[e][p][0][0];
                    float* gdst = &gib[l][e][p][0][0];
                    for (int t2 = 0; t2 < SS; ++t2) {
                        const float4* xr = reinterpret_cast<const float4*>(xs + t2 * SP);
                        float a0 = biasA, a1 = 0.f, a2 = 0.f, a3 = 0.f;
                        #pragma unroll
                        for (int j = 0; j < 8; ++j) {
                            const float4 xv = xr[j];      // uniform addr broadcast
                            a0 = fmaf(wA[4 * j + 0], xv.x, a0);
                            a1 = fmaf(wA[4 * j + 1], xv.y, a1);
                            a2 = fmaf(wA[4 * j + 2], xv.z, a2);
                            a3 = fmaf(wA[4 * j + 3], xv.w, a3);
                        }
                        gdst[t2 * GP + ln] = (a0 + a1) + (a2 + a3);
                    }
                }
            }
        } else if (wv < 9) {
            // ====== giB wave, layer l: n rows, 2 steps/iter, both elements =====
            const int l   = wv - 6;
            const int blk = n - 4 - 2 * l;
            if (blk >= 0 && blk < NBK) {
                const int p = blk & 1;
                for (int e = 0; e < EPB; ++e) {
                    const float* xs = (l == 0) ? &y3s[e][p][0][0]
                                    : (l == 1) ? &h0s[e][p][0][0]
                                               : &h1s[e][p][0][0];
                    float* gdst = &gib[l][e][p][0][0];
                    for (int t2 = 0; t2 < SS / 2; ++t2) {
                        const int tt = 2 * t2 + hh;       // half-dependent step
                        const float4* xr = reinterpret_cast<const float4*>(xs + tt * SP);
                        float a0 = biasA, a1 = 0.f, a2 = 0.f, a3 = 0.f;
                        #pragma unroll
                        for (int j = 0; j < 8; ++j) {
                            const float4 xv = xr[j];      // 2-addr broadcast (free)
                            a0 = fmaf(wA[4 * j + 0], xv.x, a0);
                            a1 = fmaf(wA[4 * j + 1], xv.y, a1);
                            a2 = fmaf(wA[4 * j + 2], xv.z, a2);
                            a3 = fmaf(wA[4 * j + 3], xv.w, a3);
                        }
                        gdst[tt * GP + 64 + lo] = (a0 + a1) + (a2 + a3);
                    }
                }
            }
        } else if (wv < 12) {
            // ====== y1/y2/y3 waves: 2 steps/iter, both elements ================
            const int s   = wv - 9;            // 0,1,2
            const int blk = n - 1 - s;
            if (blk >= 0 && blk < NBK) {
                const int p = blk & 1;
                for (int e = 0; e < EPB; ++e) {
                    const float* xs = (s == 0) ? &ebuf[e][p][0][0]
                                    : (s == 1) ? &y1s[e][p][0][0]
                                               : &y2s[e][p][0][0];
                    float* dst = (s == 0) ? &y1s[e][p][0][0]
                               : (s == 1) ? &y2s[e][p][0][0]
                                          : &y3s[e][p][0][0];
                    for (int t2 = 0; t2 < SS / 2; ++t2) {
                        const int tt = 2 * t2 + hh;       // half-dependent step
                        const float4* xr = reinterpret_cast<const float4*>(xs + tt * SP);
                        float a0 = biasA, a1 = 0.f, a2 = 0.f, a3 = 0.f;
                        #pragma unroll
                        for (int j = 0; j < 8; ++j) {
                            const float4 xv = xr[j];      // 2-addr broadcast (free)
                            a0 = fmaf(wA[4 * j + 0], xv.x, a0);
                            a1 = fmaf(wA[4 * j + 1], xv.y, a1);
                            a2 = fmaf(wA[4 * j + 2], xv.z, a2);
                            a3 = fmaf(wA[4 * j + 3], xv.w, a3);
                        }
                        const float y = fmaxf((a0 + a1) + (a2 + a3), 0.f);
                        dst[tt * SP + lo] = y;
                    }
                }
            }
        } else if (wv == 12) {
            // ====== emb gather blk n, both elements ============================
            if (n < NBK) {
                const int pe = n & 1, t0 = n * SS;
                #pragma unroll
                for (int k = 0; k < 2; ++k) {             // k = element index
                    const int task = k * 64 + ln;         // 128 tasks: 2e x 8rows x 8chunks
                    const int e   = task >> 6;
                    const int row = (task >> 3) & 7;
                    const int qq  = task & 7;
                    const int tok = xidx[(size_t)(b0 + e) * TT + t0 + row];
                    const float4 v = *reinterpret_cast<const float4*>(emb + (size_t)tok * HH + qq * 4);
                    *reinterpret_cast<float4*>(&ebuf[e][pe][row][qq * 4]) = v;
                }
            }
        }
        // wv 13-15: idle
        __syncthreads();   // one barrier per 8 steps
    }

    if (wv < 3 && ln < HH) {
        out_hf[(size_t)(wv * BB + b0    ) * HH + ln] = v_h0;
        out_hf[(size_t)(wv * BB + b0 + 1) * HH + ln] = v_h1;
    }
}

extern "C" void kernel_launch(void* const* d_in, const int* in_sizes, int n_in,
                              void* d_out, int out_size, void* d_ws, size_t ws_size,
                              hipStream_t stream) {
    const int*   x   = (const int*)  d_in[0];
    const float* hid = (const float*)d_in[1];
    const float* emb = (const float*)d_in[2];
    const float* W1  = (const float*)d_in[3];
    const float* b1  = (const float*)d_in[4];
    const float* W2  = (const float*)d_in[5];
    const float* b2  = (const float*)d_in[6];
    const float* W3  = (const float*)d_in[7];
    const float* b3  = (const float*)d_in[8];
    const float* Wih = (const float*)d_in[9];
    const float* Whh = (const float*)d_in[10];
    const float* bih = (const float*)d_in[11];
    const float* bhh = (const float*)d_in[12];

    rnn_fused<<<dim3(BB / EPB), dim3(NT), 0, stream>>>(
        x, hid, emb, W1, b1, W2, b2, W3, b3, Wih, Whh, bih, bhh, (float*)d_out);
}

// Round 20
// 335.361 us; speedup vs baseline: 1.5941x; 1.5941x over previous
//
#include <hip/hip_runtime.h>

// Problem constants (fixed by reference)
#define BB 256      // batch
#define TT 1024     // time steps
#define HH 32       // hidden
#define SS 16       // superstep length (steps per barrier)
#define NBK (TT/SS) // 64 blocks
#define NSS (NBK+9) // 73 supersteps (10-stage skew)
#define NT 1024     // 16 waves, 4/SIMD
#define SP 32       // stream row stride (floats)
#define GP 96       // gi row stride

// FINAL = R18 (best verified: 335.65us, absmax 9.77e-4), restored after R19's
// grid-starvation regression (EPB=2 halved active CUs).
//
// Architecture: one block per batch element (256 blocks = 1/CU). Layer-skewed
// 16-step superstep pipeline, one barrier per superstep. Serial GRU recurrence
// lives in 3 "gh" waves (h in registers, rlane broadcast, setprio'd); all
// feed-forward GEMV work (embedding MLP y1/y2/y3, input-side gate dots gi)
// runs in batch waves using uniform-address ds_read_b128 broadcasts.
// Weights register-resident everywhere (global reloads cost 25k cy/superstep,
// R9). Register budget per wave capped at wA[32](+wB[32])+4 accs — every
// attempt to exceed it (v2f packing R14, merged gi R16, transposed-ILP R12)
// spilled to scratch catastrophically.
//
// Measured floor analysis: wall = 1024 steps x ~690cy (gh serial chain
// latency), VALUBusy 69-81%, HBM 1.5%, LDS conflicts 0, FETCH/WRITE at
// algorithmic minimum. Falsified levers: issue cuts (R18 flat), SIMD remap
// (R15 flat), EPB=2 (R19, grid-capped), register growth (R12/14/16 spill).
//
// Superstep n schedule (one barrier per superstep):
//   wv12 : emb gather blk n     -> ebuf
//   wv9  : y1  blk n-1          -> y1s    (2 steps/iter)
//   wv10 : y2  blk n-2          -> y2s    (2 steps/iter)
//   wv11 : y3  blk n-3          -> y3s    (2 steps/iter)
//   wv3/6: gi0 A/B blk n-4      -> gib[0] (B: 2 steps/iter)
//   wv0  : gh0+gates blk n-5    -> h0s    (16 serial steps, PRIO)
//   wv4/7: gi1 A/B blk n-6      -> gib[1]
//   wv1  : gh1+gates blk n-7    -> h1s                        (PRIO)
//   wv5/8: gi2 A/B blk n-8      -> gib[2]
//   wv2  : gh2+gates blk n-9    -> out_seq                    (PRIO)
//   wv13-15: idle (barrier only)

__device__ __forceinline__ float fast_rcp(float x) { return __builtin_amdgcn_rcpf(x); }
__device__ __forceinline__ float sigm(float x)     { return fast_rcp(1.f + __expf(-x)); }
__device__ __forceinline__ float tanh_fast(float x){ float e = __expf(2.f * x); return 1.f - 2.f * fast_rcp(e + 1.f); }
__device__ __forceinline__ float rlane(float v, int k) {
    return __int_as_float(__builtin_amdgcn_readlane(__float_as_int(v), k));
}

__global__ __launch_bounds__(NT, 4) void rnn_fused(
    const int*   __restrict__ xidx,   // [B,T]
    const float* __restrict__ hid,    // [L,B,H]
    const float* __restrict__ emb,    // [38000,H]
    const float* __restrict__ W1, const float* __restrict__ b1,
    const float* __restrict__ W2, const float* __restrict__ b2,
    const float* __restrict__ W3, const float* __restrict__ b3,
    const float* __restrict__ Wih,    // [L,3H,H]
    const float* __restrict__ Whh,    // [L,3H,H]
    const float* __restrict__ bih,    // [L,3H]
    const float* __restrict__ bhh,    // [L,3H]
    float*       __restrict__ out)    // [B*T*H] ++ [L*B*H]
{
    const int b   = blockIdx.x;
    const int tid = threadIdx.x;
    const int wv  = tid >> 6;
    const int ln  = tid & 63;
    const int lo  = ln & 31;
    const int hh  = ln >> 5;           // lane half: step offset for paired waves

    __shared__ alignas(16) float ebuf[2][SS][SP];
    __shared__ alignas(16) float y1s [2][SS][SP];
    __shared__ alignas(16) float y2s [2][SS][SP];
    __shared__ alignas(16) float y3s [2][SS][SP];
    __shared__ alignas(16) float h0s [2][SS][SP];
    __shared__ alignas(16) float h1s [2][SS][SP];
    __shared__ alignas(16) float gib [3][2][SS][GP];

    // ---------------- per-role register-resident weights ----------------
    float wA[32], wB[32];
    float biasA = 0.f, biasB = 0.f, v_h = 0.f;

    if (wv < 3) {                       // gh: Whh rows {ln} and {64+lo}
        const float4* pA = reinterpret_cast<const float4*>(Whh + (size_t)(wv * 96 + ln) * HH);
        const float4* pB = reinterpret_cast<const float4*>(Whh + (size_t)(wv * 96 + 64 + lo) * HH);
        #pragma unroll
        for (int i = 0; i < 8; ++i) {
            reinterpret_cast<float4*>(wA)[i] = pA[i];
            reinterpret_cast<float4*>(wB)[i] = pB[i];
        }
        biasA = bhh[wv * 96 + ln];
        biasB = bhh[wv * 96 + 64 + lo];
        if (ln < HH) v_h = hid[(size_t)(wv * BB + b) * HH + ln];
    } else if (wv < 6) {                // giA: Wih row ln (rows 0-63)
        const int l = wv - 3;
        const float4* pA = reinterpret_cast<const float4*>(Wih + (size_t)(l * 96 + ln) * HH);
        #pragma unroll
        for (int i = 0; i < 8; ++i) reinterpret_cast<float4*>(wA)[i] = pA[i];
        biasA = bih[l * 96 + ln];
    } else if (wv < 9) {                // giB: Wih row 64+lo (n rows; 2 steps/iter)
        const int l = wv - 6;
        const float4* pA = reinterpret_cast<const float4*>(Wih + (size_t)(l * 96 + 64 + lo) * HH);
        #pragma unroll
        for (int i = 0; i < 8; ++i) reinterpret_cast<float4*>(wA)[i] = pA[i];
        biasA = bih[l * 96 + 64 + lo];
    } else if (wv < 12) {               // y1/y2/y3: W row lo (2 steps/iter)
        const float* Ws = (wv == 9) ? W1 : (wv == 10) ? W2 : W3;
        const float* bs = (wv == 9) ? b1 : (wv == 10) ? b2 : b3;
        const float4* pA = reinterpret_cast<const float4*>(Ws + (size_t)lo * HH);
        #pragma unroll
        for (int i = 0; i < 8; ++i) reinterpret_cast<float4*>(wA)[i] = pA[i];
        biasA = bs[lo];
    }
    __syncthreads();

    float* const out_seq = out + (size_t)b * TT * HH;
    float* const out_hf  = out + (size_t)BB * TT * HH;

    for (int n = 0; n < NSS; ++n) {
        if (wv < 3) {
            // ============ gh wave, layer wv: 16 serial recurrence steps ========
            const int blk = n - 5 - 2 * wv;
            if (blk >= 0 && blk < NBK) {
                const int p = blk & 1;
                const float* gsrc = &gib[wv][p][0][0];
                __builtin_amdgcn_s_setprio(1);           // critical serial wave
                for (int t2 = 0; t2 < SS; ++t2) {
                    const float giA = gsrc[t2 * GP + ln];        // r/z rows
                    const float giB = gsrc[t2 * GP + 64 + lo];   // n rows
                    float a0 = biasA, a1 = 0.f, c0 = biasB, c1 = 0.f;
                    #pragma unroll
                    for (int k = 0; k < 32; k += 2) {
                        const float h0 = rlane(v_h, k), h1 = rlane(v_h, k + 1);
                        a0 = fmaf(wA[k],     h0, a0);
                        a1 = fmaf(wA[k + 1], h1, a1);
                        c0 = fmaf(wB[k],     h0, c0);
                        c1 = fmaf(wB[k + 1], h1, c1);
                    }
                    const float sA  = giA + a0 + a1;     // r-pre / z-pre
                    const float ghB = c0 + c1;           // h_n
                    const float zp  = __shfl_xor(sA, 32);
                    const float r   = sigm(sA);
                    const float z   = sigm(zp);
                    const float nn  = tanh_fast(fmaf(r, ghB, giB));
                    const float hn  = fmaf(z, v_h - nn, nn);
                    v_h = hn;
                    if (ln < HH) {
                        if (wv == 0)      h0s[p][t2][ln] = hn;
                        else if (wv == 1) h1s[p][t2][ln] = hn;
                        else out_seq[(size_t)(blk * SS + t2) * HH + ln] = hn;
                    }
                }
                __builtin_amdgcn_s_setprio(0);
            }
        } else if (wv < 6) {
            // ============ giA wave, layer l: rows 0-63, uniform-b128 broadcast =
            const int l   = wv - 3;
            const int blk = n - 4 - 2 * l;
            if (blk >= 0 && blk < NBK) {
                const int p = blk & 1;
                const float* xs = (l == 0) ? &y3s[p][0][0]
                                : (l == 1) ? &h0s[p][0][0]
                                           : &h1s[p][0][0];
                float* gdst = &gib[l][p][0][0];
                for (int t2 = 0; t2 < SS; ++t2) {
                    const float4* xr = reinterpret_cast<const float4*>(xs + t2 * SP);
                    float a0 = biasA, a1 = 0.f, a2 = 0.f, a3 = 0.f;
                    #pragma unroll
                    for (int j = 0; j < 8; ++j) {
                        const float4 xv = xr[j];          // uniform addr -> broadcast
                        a0 = fmaf(wA[4 * j + 0], xv.x, a0);
                        a1 = fmaf(wA[4 * j + 1], xv.y, a1);
                        a2 = fmaf(wA[4 * j + 2], xv.z, a2);
                        a3 = fmaf(wA[4 * j + 3], xv.w, a3);
                    }
                    gdst[t2 * GP + ln] = (a0 + a1) + (a2 + a3);
                }
            }
        } else if (wv < 9) {
            // ============ giB wave, layer l: n rows, 2 steps per iteration =====
            const int l   = wv - 6;
            const int blk = n - 4 - 2 * l;
            if (blk >= 0 && blk < NBK) {
                const int p = blk & 1;
                const float* xs = (l == 0) ? &y3s[p][0][0]
                                : (l == 1) ? &h0s[p][0][0]
                                           : &h1s[p][0][0];
                float* gdst = &gib[l][p][0][0];
                for (int t2 = 0; t2 < SS / 2; ++t2) {
                    const int tt = 2 * t2 + hh;           // half-dependent step
                    const float4* xr = reinterpret_cast<const float4*>(xs + tt * SP);
                    float a0 = biasA, a1 = 0.f, a2 = 0.f, a3 = 0.f;
                    #pragma unroll
                    for (int j = 0; j < 8; ++j) {
                        const float4 xv = xr[j];          // 2-addr broadcast (free)
                        a0 = fmaf(wA[4 * j + 0], xv.x, a0);
                        a1 = fmaf(wA[4 * j + 1], xv.y, a1);
                        a2 = fmaf(wA[4 * j + 2], xv.z, a2);
                        a3 = fmaf(wA[4 * j + 3], xv.w, a3);
                    }
                    gdst[tt * GP + 64 + lo] = (a0 + a1) + (a2 + a3);  // all 64 lanes
                }
            }
        } else if (wv < 12) {
            // ============ y1/y2/y3 waves: 2 steps per iteration ================
            const int s   = wv - 9;            // 0,1,2
            const int blk = n - 1 - s;
            if (blk >= 0 && blk < NBK) {
                const int p = blk & 1;
                const float* xs = (s == 0) ? &ebuf[p][0][0]
                                : (s == 1) ? &y1s[p][0][0]
                                           : &y2s[p][0][0];
                float* dst = (s == 0) ? &y1s[p][0][0]
                           : (s == 1) ? &y2s[p][0][0]
                                      : &y3s[p][0][0];
                for (int t2 = 0; t2 < SS / 2; ++t2) {
                    const int tt = 2 * t2 + hh;           // half-dependent step
                    const float4* xr = reinterpret_cast<const float4*>(xs + tt * SP);
                    float a0 = biasA, a1 = 0.f, a2 = 0.f, a3 = 0.f;
                    #pragma unroll
                    for (int j = 0; j < 8; ++j) {
                        const float4 xv = xr[j];          // 2-addr broadcast (free)
                        a0 = fmaf(wA[4 * j + 0], xv.x, a0);
                        a1 = fmaf(wA[4 * j + 1], xv.y, a1);
                        a2 = fmaf(wA[4 * j + 2], xv.z, a2);
                        a3 = fmaf(wA[4 * j + 3], xv.w, a3);
                    }
                    const float y = fmaxf((a0 + a1) + (a2 + a3), 0.f);
                    dst[tt * SP + lo] = y;                // all 64 lanes store
                }
            }
        } else if (wv == 12) {
            // ============ emb gather blk n =====================================
            if (n < NBK) {
                const int pe = n & 1, t0 = n * SS;
                #pragma unroll
                for (int k = 0; k < 2; ++k) {
                    const int task = k * 64 + ln;   // 128 tasks: 16 rows x 8 chunks
                    const int row = task >> 3, qq = task & 7;
                    const int tok = xidx[b * TT + t0 + row];
                    const float4 v = *reinterpret_cast<const float4*>(emb + (size_t)tok * HH + qq * 4);
                    *reinterpret_cast<float4*>(&ebuf[pe][row][qq * 4]) = v;
                }
            }
        }
        // wv 13-15: idle
        __syncthreads();   // one barrier per 16 steps
    }

    if (wv < 3 && ln < HH)
        out_hf[(size_t)(wv * BB + b) * HH + ln] = v_h;
}

extern "C" void kernel_launch(void* const* d_in, const int* in_sizes, int n_in,
                              void* d_out, int out_size, void* d_ws, size_t ws_size,
                              hipStream_t stream) {
    const int*   x   = (const int*)  d_in[0];
    const float* hid = (const float*)d_in[1];
    const float* emb = (const float*)d_in[2];
    const float* W1  = (const float*)d_in[3];
    const float* b1  = (const float*)d_in[4];
    const float* W2  = (const float*)d_in[5];
    const float* b2  = (const float*)d_in[6];
    const float* W3  = (const float*)d_in[7];
    const float* b3  = (const float*)d_in[8];
    const float* Wih = (const float*)d_in[9];
    const float* Whh = (const float*)d_in[10];
    const float* bih = (const float*)d_in[11];
    const float* bhh = (const float*)d_in[12];

    rnn_fused<<<dim3(BB), dim3(NT), 0, stream>>>(
        x, hid, emb, W1, b1, W2, b2, W3, b3, Wih, Whh, bih, bhh, (float*)d_out);
}